// Round 1
// baseline (10139.541 us; speedup 1.0000x reference)
//
#include <hip/hip_runtime.h>

// FlashRNN fused LSTM layer, MI355X persistent-kernel implementation.
//
// Shapes: B=16, T=1024, NG=4 (i,f,z,o), NH=1, D=768. All fp32.
// per step: gates[b,g,e] = Wx[b,t,g,e] + sum_d h[b,d]*R[g,d,e] + bias[g,e]
//           c' = sig(f)*c + sig(i)*tanh(z); h' = sig(o)*tanh(c')
// out[2][B][T+1][1][D]: out[0]=h history, out[1]=c history.
//
// Design:
//  - 256 persistent WGs x 256 thr (1/CU). WG w owns d0=3w..3w+2 (12 gate-cols).
//  - R register-stationary: lane (gate g = lane>>4, kg = lane&15) holds
//    R[g][k][d0..d0+2] for its 48 k values (144 VGPRs), loaded once.
//  - wave = batch quad (4 waves x 4 b = 16 b). Per step per lane:
//    48 dwordx4 h-loads + 288 v_pk_fma_f32 (k packed in pairs).
//  - cross-kg (16-lane) reduction with DPP row_ror rotate-reduce (VALU pipe).
//  - h history == out[0] itself (fresh addresses each step -> no stale-cache
//    hazard); h published with agent-scope relaxed atomic stores (to L3),
//    then per-WG monotonic flag. 0xAA poison == negative int -> safe.
//  - one agent acquire fence (buffer_inv) per WG per step before h loads.

typedef float f32x2 __attribute__((ext_vector_type(2)));
typedef float f32x4 __attribute__((ext_vector_type(4)));

#define NWG    256
#define NTHR   256
#define TSTEPS 1024
#define BATCH  16
#define DDIM   768
#define NGATE  4
#define DPW    3            // d-columns owned per WG
#define TP1    (TSTEPS + 1)

static_assert(NWG * DPW == DDIM, "column partition must cover D");

__device__ __forceinline__ float sigm(float x) {
  return 1.0f / (1.0f + __expf(-x));
}
__device__ __forceinline__ float tanh_f(float x) {
  float e = __expf(2.0f * x);          // +inf / 0 at extremes -> +/-1, safe
  return 1.0f - 2.0f / (e + 1.0f);
}

template <int CTRL>
__device__ __forceinline__ float dpp_ror_add(float x) {
  int xi = __builtin_bit_cast(int, x);
  int yi = __builtin_amdgcn_update_dpp(0, xi, CTRL, 0xF, 0xF, false);
  return x + __builtin_bit_cast(float, yi);
}
// sum over the 16 lanes of a DPP row (all lanes end with the total)
__device__ __forceinline__ float row_reduce16(float x) {
  x = dpp_ror_add<0x128>(x);   // row_ror:8
  x = dpp_ror_add<0x124>(x);   // row_ror:4
  x = dpp_ror_add<0x122>(x);   // row_ror:2
  x = dpp_ror_add<0x121>(x);   // row_ror:1
  return x;
}

__global__ __launch_bounds__(NTHR, 1) void flashrnn_fused(
    const float* __restrict__ states,   // [2][16][1][768]
    const float* __restrict__ Wx,       // [16][1024][4][1][768]
    const float* __restrict__ Rw,       // [4][1][768][768]  (R[g][d_in][d_out])
    const float* __restrict__ bias,     // [4][1][768]
    float* __restrict__ out,            // [2][16][1025][1][768]
    int* flags)                         // [256] in d_ws (poisoned 0xAA -> negative)
{
  const int wg   = blockIdx.x;
  const int tid  = threadIdx.x;
  const int wv   = tid >> 6;       // wave 0..3 -> batch quad
  const int lane = tid & 63;
  const int g    = lane >> 4;      // gate 0..3
  const int kg   = lane & 15;      // k-group 0..15
  const int d0   = wg * DPW;

  __shared__ float gates_lds[NGATE * DPW * BATCH];   // [g][dd][b]

  // ---- one-time: load stationary R fragment into registers -------------
  // lane's k set: { 256*s + 4*kg + 64*c + j : s<3, c<4, j<4 }  (48 values)
  // stored as k-pairs for packed fp32 math.
  f32x2 r2[3][4][3][2];
  #pragma unroll
  for (int s = 0; s < 3; ++s)
    #pragma unroll
    for (int c = 0; c < 4; ++c) {
      const int kb = 256 * s + 4 * kg + 64 * c;
      #pragma unroll
      for (int e = 0; e < 3; ++e)
        #pragma unroll
        for (int p = 0; p < 2; ++p) {
          float lo = Rw[(size_t)(g * DDIM + kb + 2 * p    ) * DDIM + d0 + e];
          float hi = Rw[(size_t)(g * DDIM + kb + 2 * p + 1) * DDIM + d0 + e];
          f32x2 v; v.x = lo; v.y = hi;
          r2[s][c][e][p] = v;
        }
    }

  // ---- update-thread state (threads 0..47: dd = tid>>4, b = tid&15) ----
  const int dd = tid >> 4;
  const int bb = tid & 15;
  float c_reg = 0.0f;
  float b4[4] = {0.f, 0.f, 0.f, 0.f};

  if (tid < DPW * BATCH) {
    #pragma unroll
    for (int gg = 0; gg < 4; ++gg) b4[gg] = bias[gg * DDIM + d0 + dd];
    float h0 = states[(size_t)bb * DDIM + d0 + dd];
    c_reg    = states[(size_t)(BATCH + bb) * DDIM + d0 + dd];
    // t=0 outputs; h0 must be agent-visible (it seeds every WG's first matvec)
    __hip_atomic_store(&out[((size_t)bb * TP1 + 0) * DDIM + d0 + dd], h0,
                       __ATOMIC_RELAXED, __HIP_MEMORY_SCOPE_AGENT);
    out[((size_t)(BATCH + bb) * TP1 + 0) * DDIM + d0 + dd] = c_reg;
  }
  __syncthreads();   // drains vmcnt before flag publish
  if (tid == 0)
    __hip_atomic_store(&flags[wg], 1, __ATOMIC_RELAXED, __HIP_MEMORY_SCOPE_AGENT);

  // ---- main recurrence --------------------------------------------------
  for (int t = 0; t < TSTEPS; ++t) {
    // wait until every WG has published h_t  (flags[*] >= t+1)
    const int target = t + 1;
    for (;;) {
      int f = __hip_atomic_load(&flags[tid], __ATOMIC_RELAXED,
                                __HIP_MEMORY_SCOPE_AGENT);
      if (__syncthreads_and(f >= target)) break;
      __builtin_amdgcn_s_sleep(2);
    }
    if (tid == 0) __builtin_amdgcn_fence(__ATOMIC_ACQUIRE, "agent");
    __syncthreads();

    // Wx for this step (only the 48 update threads need it; issued early,
    // consumed after the matvec -> latency hidden)
    float wx[4];
    if (tid < DPW * BATCH) {
      #pragma unroll
      for (int gg = 0; gg < 4; ++gg)
        wx[gg] = Wx[(((size_t)bb * TSTEPS + t) * NGATE + gg) * DDIM + d0 + dd];
    }

    // matvec: acc[e][q] = sum over lane's k of h[b][k] * R[g][k][d0+e]
    f32x2 acc2[3][4];
    #pragma unroll
    for (int e = 0; e < 3; ++e)
      #pragma unroll
      for (int q = 0; q < 4; ++q) { acc2[e][q].x = 0.f; acc2[e][q].y = 0.f; }

    #pragma unroll
    for (int q = 0; q < 4; ++q) {
      const int b = 4 * wv + q;
      const float* hrow = out + ((size_t)b * TP1 + t) * DDIM;  // h_t row
      f32x4 h4[12];
      #pragma unroll
      for (int s = 0; s < 3; ++s)
        #pragma unroll
        for (int c = 0; c < 4; ++c)
          h4[s * 4 + c] = *(const f32x4*)(hrow + 256 * s + 4 * kg + 64 * c);
      #pragma unroll
      for (int s = 0; s < 3; ++s)
        #pragma unroll
        for (int c = 0; c < 4; ++c) {
          f32x2 ha; ha.x = h4[s * 4 + c].x; ha.y = h4[s * 4 + c].y;
          f32x2 hb; hb.x = h4[s * 4 + c].z; hb.y = h4[s * 4 + c].w;
          #pragma unroll
          for (int e = 0; e < 3; ++e) {
            acc2[e][q] = __builtin_elementwise_fma(ha, r2[s][c][e][0], acc2[e][q]);
            acc2[e][q] = __builtin_elementwise_fma(hb, r2[s][c][e][1], acc2[e][q]);
          }
        }
    }

    // reduce over the 16 kg lanes; writer lane kg==0 deposits to LDS
    #pragma unroll
    for (int e = 0; e < 3; ++e)
      #pragma unroll
      for (int q = 0; q < 4; ++q) {
        float v = acc2[e][q].x + acc2[e][q].y;
        v = row_reduce16(v);
        if (kg == 0) gates_lds[(g * DPW + e) * BATCH + 4 * wv + q] = v;
      }
    __syncthreads();

    // pointwise LSTM update + publish h_{t+1}
    if (tid < DPW * BATCH) {
      const float pi = wx[0] + gates_lds[(0 * DPW + dd) * BATCH + bb] + b4[0];
      const float pf = wx[1] + gates_lds[(1 * DPW + dd) * BATCH + bb] + b4[1];
      const float pz = wx[2] + gates_lds[(2 * DPW + dd) * BATCH + bb] + b4[2];
      const float po = wx[3] + gates_lds[(3 * DPW + dd) * BATCH + bb] + b4[3];
      const float ig = sigm(pi);
      const float fg = sigm(pf);
      const float zg = tanh_f(pz);
      const float og = sigm(po);
      c_reg = fg * c_reg + ig * zg;
      const float hn = og * tanh_f(c_reg);
      __hip_atomic_store(&out[((size_t)bb * TP1 + (t + 1)) * DDIM + d0 + dd], hn,
                         __ATOMIC_RELAXED, __HIP_MEMORY_SCOPE_AGENT);
      out[((size_t)(BATCH + bb) * TP1 + (t + 1)) * DDIM + d0 + dd] = c_reg;
    }
    __syncthreads();   // drains all publish stores (vmcnt(0) before s_barrier)
    if (tid == 0)
      __hip_atomic_store(&flags[wg], t + 2, __ATOMIC_RELAXED,
                         __HIP_MEMORY_SCOPE_AGENT);
  }
}

extern "C" void kernel_launch(void* const* d_in, const int* in_sizes, int n_in,
                              void* d_out, int out_size, void* d_ws, size_t ws_size,
                              hipStream_t stream) {
  const float* states = (const float*)d_in[0];
  const float* Wx     = (const float*)d_in[1];
  const float* Rw     = (const float*)d_in[2];
  const float* bias   = (const float*)d_in[3];
  float* out          = (float*)d_out;
  int* flags          = (int*)d_ws;   // 1 KB; 0xAA poison reads as negative

  flashrnn_fused<<<dim3(NWG), dim3(NTHR), 0, stream>>>(states, Wx, Rw, bias,
                                                       out, flags);
}